// Round 2
// baseline (6405.125 us; speedup 1.0000x reference)
//
#include <hip/hip_runtime.h>
#include <math.h>

// Sizes (fixed by the problem)
#define B_ 32
#define S_ 64
#define T_ 64
#define EMB_ 256
#define HID_ 512
#define VSZ_ 32000

// ---------------------------------------------------------------------------
// Workspace layout (floats). Total ~12.7M floats = 50.8 MB.
//  xw_f/xw_b [64][512 hcol][32 b][4 g]   (gate-last so updater reads float4)
//  hscat     [64][32][1024]
//  encout    [32][64][512]
//  ctx       [32][512]
//  hinitT    [512][32]                   (transposed h_init for decoder)
//  hdec      [63][32][512]
//  hbuf_enc  [2 parity][2 dir][512][32]  (transposed h ping-pong)
//  hbuf_dec  [2 parity][512][32]
//  bar       32 ints (16 enc + 16 dec barrier lines)
//  pre aliases xw_f (dead after encoder)
// ---------------------------------------------------------------------------
#define O_XWF    0
#define O_XWB    4194304
#define O_HSCAT  8388608
#define O_ENCOUT 10485760
#define O_CTX    11534336
#define O_HINIT  11550720
#define O_HDEC   11567104
#define O_HBUFE  12599296
#define O_HBUFD  12664832
#define O_BAR    12697600

// ---------------------------------------------------------------------------
// Zero the barrier counters (ws is re-poisoned 0xAA before every launch)
// ---------------------------------------------------------------------------
__global__ __launch_bounds__(64) void k_binit(int* __restrict__ bar)
{
    if (threadIdx.x < 32) bar[threadIdx.x] = 0;
}

// ---------------------------------------------------------------------------
// Generic tiled fp32 GEMM-TN: C[M][N] = A[M][K] * W[N][K]^T + bias.
// MODE 0: enc input proj (z=dir). A = enc_emb[src], C = xw [s][hcol][b][g]
// MODE 1: enc_out + h_init.       A = hscat, C = encout / tanh -> hinitT
// MODE 2: dec precompute.         A = [dec_emb[tgt], ctx], C = pre (as xw)
// MODE 3: vocab projection.       A = hdec, C = out[b][t+1][v]
// ---------------------------------------------------------------------------
template<int MODE, int K>
__global__ __launch_bounds__(256) void k_gemm(
    const float* __restrict__ A0, const float* __restrict__ A1,
    const int*   __restrict__ I0,
    const float* __restrict__ W0, const float* __restrict__ W1,
    const float* __restrict__ bias0, const float* __restrict__ bias1,
    float* __restrict__ C0, float* __restrict__ C1, float* __restrict__ C2,
    int M)
{
    __shared__ float As[16][132];
    __shared__ float Bs[16][132];

    const int t = threadIdx.x;
    const int m0 = blockIdx.y * 128;
    const int n0 = blockIdx.x * 128;
    const int z = blockIdx.z;
    const int tm8 = (t >> 4) * 8;
    const int tn8 = (t & 15) * 8;

    const float* W    = (MODE == 0 && z == 1) ? W1 : W0;
    const float* Bp   = (MODE == 0 && z == 1) ? bias1 : bias0;
    float*       Cout = (MODE == 0 && z == 1) ? C1 : C0;

    auto loadA = [&](int r, int k) -> float4 {
        if constexpr (MODE == 0) {
            int s = r >> 5, b = r & 31;
            int id = I0[b * 64 + s];
            return *(const float4*)&A0[(size_t)id * 256 + k];
        } else if constexpr (MODE == 1) {
            if (r < 2048) {
                int b = r >> 6, s = r & 63;
                return *(const float4*)&A0[s * 32768 + b * 1024 + k];
            } else {
                int b = r - 2048;   // hT rows: fwd final = hs[63], bwd final = hs[0]
                return *(const float4*)&A0[(k < 512 ? 63 * 32768 : 0) + b * 1024 + k];
            }
        } else if constexpr (MODE == 2) {
            int tt = r >> 5, b = r & 31;
            if (k < 256) {
                int id = I0[b * 64 + tt];
                return *(const float4*)&A0[(size_t)id * 256 + k];
            } else {
                return *(const float4*)&A1[b * 512 + (k - 256)];
            }
        } else {
            return *(const float4*)&A0[(size_t)r * 512 + k];
        }
    };

    float acc[8][8];
    #pragma unroll
    for (int i = 0; i < 8; ++i)
        #pragma unroll
        for (int j = 0; j < 8; ++j) acc[i][j] = 0.f;

    for (int k0 = 0; k0 < K; k0 += 16) {
        #pragma unroll
        for (int i2 = 0; i2 < 2; ++i2) {
            int slot = t + i2 * 256;         // 512 float4 slots per tile
            int rl = slot >> 2, kq = slot & 3;
            int kk0 = k0 + kq * 4;
            float4 av = make_float4(0.f, 0.f, 0.f, 0.f);
            if (m0 + rl < M) av = loadA(m0 + rl, kk0);
            As[kq * 4 + 0][rl] = av.x; As[kq * 4 + 1][rl] = av.y;
            As[kq * 4 + 2][rl] = av.z; As[kq * 4 + 3][rl] = av.w;
            float4 bv = *(const float4*)&W[(size_t)(n0 + rl) * K + kk0];
            Bs[kq * 4 + 0][rl] = bv.x; Bs[kq * 4 + 1][rl] = bv.y;
            Bs[kq * 4 + 2][rl] = bv.z; Bs[kq * 4 + 3][rl] = bv.w;
        }
        __syncthreads();
        #pragma unroll
        for (int kk = 0; kk < 16; ++kk) {
            float a[8], b[8];
            *(float4*)&a[0] = *(const float4*)&As[kk][tm8];
            *(float4*)&a[4] = *(const float4*)&As[kk][tm8 + 4];
            *(float4*)&b[0] = *(const float4*)&Bs[kk][tn8];
            *(float4*)&b[4] = *(const float4*)&Bs[kk][tn8 + 4];
            #pragma unroll
            for (int i = 0; i < 8; ++i)
                #pragma unroll
                for (int j = 0; j < 8; ++j)
                    acc[i][j] = fmaf(a[i], b[j], acc[i][j]);
        }
        __syncthreads();
    }

    #pragma unroll
    for (int i = 0; i < 8; ++i) {
        int r = m0 + tm8 + i;
        if (r >= M) break;
        #pragma unroll
        for (int j = 0; j < 8; ++j) {
            int n = n0 + tn8 + j;
            float v = acc[i][j] + Bp[n];
            if constexpr (MODE == 0) {
                int s = r >> 5, b = r & 31;
                Cout[s * 65536 + (n & 511) * 128 + b * 4 + (n >> 9)] = v;
            } else if constexpr (MODE == 1) {
                if (r < 2048) Cout[r * 512 + n] = v;
                else          C2[n * 32 + (r - 2048)] = tanhf(v);  // transposed
            } else if constexpr (MODE == 2) {
                int tt = r >> 5, b = r & 31;
                Cout[tt * 65536 + (n & 511) * 128 + b * 4 + (n >> 9)] = v;
            } else {
                int tt = r >> 5, b = r & 31;
                Cout[(size_t)b * 2048000 + (size_t)(tt + 1) * 32000 + n] = v;
            }
        }
    }
}

// ---------------------------------------------------------------------------
// Persistent LSTM recurrence. MODE 0: encoder (grid 512 = 2 dir x 256 blocks),
// MODE 1: decoder (grid 256). Each block owns 8 gate-cols (2 h-cols x 4 gates),
// keeps its 8 Whh rows in LDS for all steps. h ping-pongs through global in
// transposed [k][b] layout; one device-wide barrier per step (16-line atomic
// counters + threadfence release/acquire for cross-XCD coherence).
// ---------------------------------------------------------------------------
template<int MODE>
__global__ __launch_bounds__(256, 2) void k_rnn(
    const float* __restrict__ xw0, const float* __restrict__ xw1,
    const float* __restrict__ W0,  const float* __restrict__ W1,
    const float* __restrict__ hinitT,
    float* __restrict__ hbuf,          // [2][ndir][512][32]
    float* __restrict__ hout,          // enc: hscat; dec: hdec
    int* __restrict__ bar, int nsteps)
{
    __shared__ float wls[8][516];      // 8 gate-rows x 512 k (pad 516)
    __shared__ float hls[256][36];     // k-phase buffer of h, [k][b] pad 36
    __shared__ float sums[4][8][36];   // per-wave k-split partials

    const int t = threadIdx.x;
    const int nblk = gridDim.x;
    const int dir = (MODE == 0) ? (int)(blockIdx.x >> 8) : 0;
    const int bi  = blockIdx.x & 255;
    const int hc0 = bi * 2;
    const int ndir = (MODE == 0) ? 2 : 1;
    const float* xw = (MODE == 0 && dir) ? xw1 : xw0;
    const float* W  = (MODE == 0 && dir) ? W1 : W0;

    // Stage weights once: row j = g*512 + hc0 + hcl, gc index = hcl*4+g
    #pragma unroll
    for (int i = 0; i < 4; ++i) {
        int q = i * 256 + t;                  // 1024 float4 slots
        int rr = q >> 7, c4 = (q & 127) << 2;
        int hcl = rr >> 2, g = rr & 3;
        float4 v = *(const float4*)&W[(size_t)(g * 512 + hc0 + hcl) * 512 + c4];
        *(float4*)&wls[rr][c4] = v;
    }

    const int w = t >> 6, l = t & 63, bq = l & 7, gcl = l >> 3;
    float c0 = 0.f;                            // cell state (updater threads)

    for (int it = 0; it < nsteps; ++it) {
        int s = (MODE == 0) ? (dir ? 63 - it : it) : it;
        float4 acc = make_float4(0.f, 0.f, 0.f, 0.f);
        bool have_h = (MODE == 1) || (it > 0);
        if (have_h) {
            const float* hprev = (MODE == 1 && it == 0) ? hinitT
                : hbuf + (((it - 1) & 1) * ndir + dir) * 16384;
            #pragma unroll 1
            for (int p = 0; p < 2; ++p) {
                __syncthreads();               // hls free to overwrite
                #pragma unroll
                for (int i = 0; i < 8; ++i) {
                    int q = i * 256 + t;       // 2048 float4
                    int kk = q >> 3, b4 = (q & 7) << 2;
                    float4 v = *(const float4*)&hprev[(p * 256 + kk) * 32 + b4];
                    *(float4*)&hls[kk][b4] = v;
                }
                __syncthreads();
                int kb = w * 64;               // this wave's k-chunk in phase
                #pragma unroll 4
                for (int qk = 0; qk < 16; ++qk) {
                    int kk = kb + qk * 4;
                    float4 wv = *(const float4*)&wls[gcl][p * 256 + kk];
                    float4 h0 = *(const float4*)&hls[kk + 0][bq * 4];
                    float4 h1 = *(const float4*)&hls[kk + 1][bq * 4];
                    float4 h2 = *(const float4*)&hls[kk + 2][bq * 4];
                    float4 h3 = *(const float4*)&hls[kk + 3][bq * 4];
                    acc.x = fmaf(h0.x, wv.x, acc.x); acc.y = fmaf(h0.y, wv.x, acc.y);
                    acc.z = fmaf(h0.z, wv.x, acc.z); acc.w = fmaf(h0.w, wv.x, acc.w);
                    acc.x = fmaf(h1.x, wv.y, acc.x); acc.y = fmaf(h1.y, wv.y, acc.y);
                    acc.z = fmaf(h1.z, wv.y, acc.z); acc.w = fmaf(h1.w, wv.y, acc.w);
                    acc.x = fmaf(h2.x, wv.z, acc.x); acc.y = fmaf(h2.y, wv.z, acc.y);
                    acc.z = fmaf(h2.z, wv.z, acc.z); acc.w = fmaf(h2.w, wv.z, acc.w);
                    acc.x = fmaf(h3.x, wv.w, acc.x); acc.y = fmaf(h3.y, wv.w, acc.y);
                    acc.z = fmaf(h3.z, wv.w, acc.z); acc.w = fmaf(h3.w, wv.w, acc.w);
                }
            }
        }
        *(float4*)&sums[w][gcl][bq * 4] = acc;
        __syncthreads();
        if (t < 64) {
            int b = t & 31, hcl = t >> 5;
            int hc = hc0 + hcl;
            float4 g4 = *(const float4*)&xw[(size_t)s * 65536 + hc * 128 + b * 4];
            float sv0 = sums[0][hcl*4+0][b] + sums[1][hcl*4+0][b] + sums[2][hcl*4+0][b] + sums[3][hcl*4+0][b];
            float sv1 = sums[0][hcl*4+1][b] + sums[1][hcl*4+1][b] + sums[2][hcl*4+1][b] + sums[3][hcl*4+1][b];
            float sv2 = sums[0][hcl*4+2][b] + sums[1][hcl*4+2][b] + sums[2][hcl*4+2][b] + sums[3][hcl*4+2][b];
            float sv3 = sums[0][hcl*4+3][b] + sums[1][hcl*4+3][b] + sums[2][hcl*4+3][b] + sums[3][hcl*4+3][b];
            float gi = g4.x + sv0, gf = g4.y + sv1, gg = g4.z + sv2, go = g4.w + sv3;
            float iv = 1.f / (1.f + expf(-gi));
            float fv = 1.f / (1.f + expf(-gf));
            float gv = tanhf(gg);
            float ov = 1.f / (1.f + expf(-go));
            float cn = fv * c0 + iv * gv;      // c0==0 at it==0
            c0 = cn;
            float hv = ov * tanhf(cn);
            hbuf[((it & 1) * ndir + dir) * 16384 + hc * 32 + b] = hv;
            if (MODE == 0) hout[s * 32768 + b * 1024 + dir * 512 + hc] = hv;
            else           hout[it * 16384 + b * 512 + hc] = hv;
        }
        // ---- device-wide barrier (skip after last step) ----
        if (it + 1 < nsteps) {
            __syncthreads();
            if (t == 0) {
                __threadfence();               // release: wb L2
                __hip_atomic_fetch_add(&bar[blockIdx.x & 15], 1,
                                       __ATOMIC_RELAXED, __HIP_MEMORY_SCOPE_AGENT);
            }
            if (t < 16) {
                int tgt = (nblk >> 4) * (it + 1);
                while (__hip_atomic_load(&bar[t], __ATOMIC_RELAXED,
                                         __HIP_MEMORY_SCOPE_AGENT) < tgt)
                    __builtin_amdgcn_s_sleep(2);
                __threadfence();               // acquire: inv L1/L2
            }
            __syncthreads();
        }
    }
}

// ---------------------------------------------------------------------------
// Attention context (constant across decoder steps: softmax over S is
// invariant to the h@w1 and attnb terms, which are constant along S).
// ---------------------------------------------------------------------------
__global__ __launch_bounds__(256) void k_ctx(
    const float* __restrict__ encout, const float* __restrict__ attnW,
    float* __restrict__ ctx)
{
    __shared__ float red[256];
    __shared__ float sc[64];
    const int b = blockIdx.x;
    const int t = threadIdx.x;
    const float* eb = encout + b * 64 * 512;
    const float* w2 = attnW + 512;

    int s = t >> 2, part = t & 3;
    float p = 0.f;
    for (int h = part * 128; h < part * 128 + 128; ++h)
        p += eb[s * 512 + h] * w2[h];
    red[t] = p;
    __syncthreads();
    if (part == 0) sc[s] = red[t] + red[t + 1] + red[t + 2] + red[t + 3];
    __syncthreads();
    if (t == 0) {
        float mx = -1e30f;
        for (int s2 = 0; s2 < 64; ++s2) mx = fmaxf(mx, sc[s2]);
        float sum = 0.f;
        for (int s2 = 0; s2 < 64; ++s2) { sc[s2] = expf(sc[s2] - mx); sum += sc[s2]; }
        float inv = 1.f / sum;
        for (int s2 = 0; s2 < 64; ++s2) sc[s2] *= inv;
    }
    __syncthreads();
    for (int h = t; h < 512; h += 256) {
        float a = 0.f;
        for (int s2 = 0; s2 < 64; ++s2) a += sc[s2] * eb[s2 * 512 + h];
        ctx[b * 512 + h] = a;
    }
}

// Zero out[:, 0, :] (harness poisons d_out; reference has zeros at t=0)
__global__ __launch_bounds__(256) void k_zero0(float* __restrict__ out)
{
    int idx = blockIdx.x * 256 + threadIdx.x;     // float4 index, 256000 total
    int b = idx / 8000, v = idx % 8000;
    ((float4*)out)[(size_t)b * 512000 + v] = make_float4(0.f, 0.f, 0.f, 0.f);
}

// ---------------------------------------------------------------------------
extern "C" void kernel_launch(void* const* d_in, const int* in_sizes, int n_in,
                              void* d_out, int out_size, void* d_ws, size_t ws_size,
                              hipStream_t stream)
{
    const int*   src     = (const int*)  d_in[0];
    const int*   tgt     = (const int*)  d_in[1];
    const float* enc_emb = (const float*)d_in[2];
    const float* dec_emb = (const float*)d_in[3];
    const float* Wih_f   = (const float*)d_in[4];
    const float* Whh_f   = (const float*)d_in[5];
    const float* b_f     = (const float*)d_in[6];
    const float* Wih_b   = (const float*)d_in[7];
    const float* Whh_b   = (const float*)d_in[8];
    const float* b_b     = (const float*)d_in[9];
    const float* encW    = (const float*)d_in[10];
    const float* encb    = (const float*)d_in[11];
    const float* dWih    = (const float*)d_in[12];
    const float* dWhh    = (const float*)d_in[13];
    const float* db      = (const float*)d_in[14];
    const float* attnW   = (const float*)d_in[15];
    const float* projW   = (const float*)d_in[17];
    const float* projb   = (const float*)d_in[18];
    float* out = (float*)d_out;
    float* ws  = (float*)d_ws;

    float* xw_f   = ws + O_XWF;
    float* xw_b   = ws + O_XWB;
    float* hscat  = ws + O_HSCAT;
    float* encout = ws + O_ENCOUT;
    float* ctx    = ws + O_CTX;
    float* hinitT = ws + O_HINIT;
    float* hdec   = ws + O_HDEC;
    float* hbufe  = ws + O_HBUFE;
    float* hbufd  = ws + O_HBUFD;
    int*   bar    = (int*)(ws + O_BAR);
    float* pre    = xw_f;                 // reuse (xw_f dead after encoder)

    // 0. Zero barrier counters
    k_binit<<<dim3(1), 64, 0, stream>>>(bar);

    // 1. Encoder input projections (both directions), bias folded in
    k_gemm<0, 256><<<dim3(16, 16, 2), 256, 0, stream>>>(
        enc_emb, nullptr, src, Wih_f, Wih_b, b_f, b_b, xw_f, xw_b, nullptr, 2048);

    // 2. Persistent bi-LSTM encoder: all 64 steps, one launch
    k_rnn<0><<<dim3(512), 256, 0, stream>>>(
        xw_f, xw_b, Whh_f, Whh_b, nullptr, hbufe, hscat, bar, 64);

    // 3. enc_out (+ transposed tanh h_init via rows 2048..2079)
    k_gemm<1, 1024><<<dim3(4, 17, 1), 256, 0, stream>>>(
        hscat, nullptr, nullptr, encW, nullptr, encb, nullptr,
        encout, nullptr, hinitT, 2080);

    // 4. Attention context (constant across decoder steps)
    k_ctx<<<dim3(32), 256, 0, stream>>>(encout, attnW, ctx);

    // 5. Decoder gate precompute: [e_t, ctx] @ dWih^T + db for all 63 steps
    k_gemm<2, 768><<<dim3(16, 16, 1), 256, 0, stream>>>(
        dec_emb, ctx, tgt, dWih, nullptr, db, nullptr, pre, nullptr, nullptr, 2016);

    // 6. Persistent decoder LSTM: all 63 steps, one launch
    k_rnn<1><<<dim3(256), 256, 0, stream>>>(
        pre, nullptr, dWhh, nullptr, hinitT, hbufd, hdec, bar + 16, 63);

    // 7. Vocab projection for all steps at once + zero t=0 slice
    k_zero0<<<dim3(1000), 256, 0, stream>>>(out);
    k_gemm<3, 512><<<dim3(250, 16, 1), 256, 0, stream>>>(
        hdec, nullptr, nullptr, projW, nullptr, projb, nullptr,
        out, nullptr, nullptr, 2016);
}